// Round 9
// baseline (227.814 us; speedup 1.0000x reference)
//
#include <hip/hip_runtime.h>

constexpr int Bn  = 4;
constexpr int Sn  = 1024;
constexpr int Dn  = 1024;
constexpr int Hn  = 16;
constexpr int HDn = 64;

using short8   = __attribute__((ext_vector_type(8))) short;
using float4v  = __attribute__((ext_vector_type(4))) float;
using float16v = __attribute__((ext_vector_type(16))) float;

__device__ __forceinline__ ushort f2bf(float f) {
    union { float f; unsigned u; } v; v.f = f;
    unsigned r = v.u + 0x7fff + ((v.u >> 16) & 1);   // RNE
    return (ushort)(r >> 16);
}

__device__ __forceinline__ void gload16(const void* g, void* l) {
    __builtin_amdgcn_global_load_lds(
        (const __attribute__((address_space(1))) void*)g,
        (__attribute__((address_space(3))) void*)l, 16, 0, 0);
}

// ---------------------------------------------------------------------------
// x (fp32) -> xb (bf16 row-major)
// ---------------------------------------------------------------------------
__global__ __launch_bounds__(256) void convert_x(const float* __restrict__ x,
                                                 ushort* __restrict__ xb)
{
    const size_t i = ((size_t)blockIdx.x * 256 + threadIdx.x) * 8;
    float4 a = *(const float4*)&x[i];
    float4 b = *(const float4*)&x[i + 4];
    ushort o[8] = {f2bf(a.x), f2bf(a.y), f2bf(a.z), f2bf(a.w),
                   f2bf(b.x), f2bf(b.y), f2bf(b.z), f2bf(b.w)};
    *(uint4*)&xb[i] = *(const uint4*)o;
}

// ---------------------------------------------------------------------------
// W (K x N fp32) -> Wt (N x K bf16)
// ---------------------------------------------------------------------------
__global__ __launch_bounds__(256) void transpose_w(
    const float* __restrict__ Wq, const float* __restrict__ Wk,
    const float* __restrict__ Wv, ushort* __restrict__ Wt)
{
    const int which = blockIdx.z;
    const float* __restrict__ W = (which == 0) ? Wq : (which == 1) ? Wk : Wv;
    ushort* __restrict__ O = Wt + (size_t)which * Dn * Dn;

    const int k0 = blockIdx.x * 64;
    const int n0 = blockIdx.y * 64;
    const int t  = threadIdx.x;

    __shared__ __align__(16) ushort T[64 * 72];

    const int kl = t >> 4;
    const int nl = (t & 15) * 4;
#pragma unroll
    for (int p = 0; p < 4; ++p) {
        float4 w = *(const float4*)&W[(size_t)(k0 + p * 16 + kl) * Dn + n0 + nl];
        T[(nl + 0) * 72 + p * 16 + kl] = f2bf(w.x);
        T[(nl + 1) * 72 + p * 16 + kl] = f2bf(w.y);
        T[(nl + 2) * 72 + p * 16 + kl] = f2bf(w.z);
        T[(nl + 3) * 72 + p * 16 + kl] = f2bf(w.w);
    }
    __syncthreads();
    const int nr = t >> 2;
    const int kc = (t & 3) * 16;
    uint4 u0 = *(const uint4*)&T[nr * 72 + kc];
    uint4 u1 = *(const uint4*)&T[nr * 72 + kc + 8];
    *(uint4*)&O[(size_t)(n0 + nr) * Dn + k0 + kc]     = u0;
    *(uint4*)&O[(size_t)(n0 + nr) * Dn + k0 + kc + 8] = u1;
}

// ---------------------------------------------------------------------------
// build_mask: per-pair halfword masks (0xFFFF=keep) in PV-pack fragment order.
// rid = (((b*8+qt)*16+kt)*4+w)*64+lane; 16 words at Mb+rid*16, index mt*8+pr.
// pair pr covers keys kt*64 + mt*32 + (2pr&3) + 8*(2pr>>2) + 4*hi + {0,1};
// q = qt*128 + w*32 + (lane&31) = qsub*32+col with qsub=qt*4+w.
// ---------------------------------------------------------------------------
__global__ __launch_bounds__(256) void build_mask(const float* __restrict__ adj,
                                                  uint* __restrict__ Mb)
{
    const int rid  = blockIdx.x * 256 + threadIdx.x;
    const int lane = rid & 63;
    const int w    = (rid >> 6) & 3;
    const int kt   = (rid >> 8) & 15;
    const int qt   = (rid >> 12) & 7;
    const int b    = rid >> 15;
    const int col  = lane & 31, hi = lane >> 5;
    const int q    = qt * 128 + w * 32 + col;
    const float* arow = adj + ((size_t)b * Sn + q) * Sn + kt * 64;

    uint words[16];
#pragma unroll
    for (int mt = 0; mt < 2; ++mt)
#pragma unroll
        for (int pr = 0; pr < 8; ++pr) {
            const int r0 = 2 * pr;
            const int k0l = mt * 32 + (r0 & 3) + 8 * (r0 >> 2) + 4 * hi;
            float2 a = *(const float2*)&arow[k0l];
            words[mt * 8 + pr] = (a.x >= 0.5f ? 0x0000FFFFu : 0u) |
                                 (a.y >= 0.5f ? 0xFFFF0000u : 0u);
        }
    uint* dst = Mb + (size_t)rid * 16;
#pragma unroll
    for (int c = 0; c < 4; ++c)
        *(uint4*)&dst[c * 4] = make_uint4(words[c*4], words[c*4+1], words[c*4+2], words[c*4+3]);
}

// ---------------------------------------------------------------------------
// bf16 MFMA GEMM: Q pre-scaled by 0.125*log2(e); Q/K -> [B,H,S,HD], V -> [B,H,HD,S]
// (R7-proven version)
// ---------------------------------------------------------------------------
__global__ __launch_bounds__(256) void qkv_gemm(
    const ushort* __restrict__ xb, const ushort* __restrict__ Wt,
    const float* __restrict__ bq, const float* __restrict__ bk,
    const float* __restrict__ bv,
    ushort* __restrict__ Qb, ushort* __restrict__ Kb, ushort* __restrict__ Vb)
{
    const int which = blockIdx.z;
    const ushort* __restrict__ Bw   = Wt + (size_t)which * Dn * Dn;
    const float* __restrict__  bias = (which == 0) ? bq : (which == 1) ? bk : bv;
    ushort* __restrict__       Out  = (which == 0) ? Qb : (which == 1) ? Kb : Vb;
    const float scale = (which == 0) ? 0.18033688011112042f : 1.0f;  // 0.125*log2(e)

    const int n0   = blockIdx.x * 128;
    const int m0   = blockIdx.y * 128;
    const int tid  = threadIdx.x;
    const int wave = tid >> 6;
    const int lane = tid & 63;
    const int wm   = wave >> 1;
    const int wn   = wave & 1;

    __shared__ __align__(16) ushort As[128 * 32];
    __shared__ __align__(16) ushort Bs[128 * 32];

    const int L0 = wave * 64 + lane;
    const int r0s = L0 >> 2, c0s = (L0 & 3) * 8;
    const int L1 = L0 + 256;
    const int r1s = L1 >> 2, c1s = (L1 & 3) * 8;

    const ushort* pA0 = &xb[(size_t)(m0 + r0s) * Dn + c0s];
    const ushort* pA1 = &xb[(size_t)(m0 + r1s) * Dn + c1s];
    const ushort* pB0 = &Bw[(size_t)(n0 + r0s) * Dn + c0s];
    const ushort* pB1 = &Bw[(size_t)(n0 + r1s) * Dn + c1s];

    char* ldsA0 = (char*)As + wave * 1024;
    char* ldsA1 = (char*)As + wave * 1024 + 4096;
    char* ldsB0 = (char*)Bs + wave * 1024;
    char* ldsB1 = (char*)Bs + wave * 1024 + 4096;

    const int mlane = lane & 15;
    const int kg    = (lane >> 4) * 8;

    float4v acc[4][4];
    const float4v z4 = {0.f, 0.f, 0.f, 0.f};
#pragma unroll
    for (int i = 0; i < 4; ++i)
#pragma unroll
        for (int j = 0; j < 4; ++j) acc[i][j] = z4;

    for (int k0 = 0; k0 < Dn; k0 += 32) {
        __syncthreads();
        gload16(pA0, ldsA0);
        gload16(pA1, ldsA1);
        gload16(pB0, ldsB0);
        gload16(pB1, ldsB1);
        pA0 += 32; pA1 += 32; pB0 += 32; pB1 += 32;
        __syncthreads();

        short8 af[4], bf[4];
#pragma unroll
        for (int i = 0; i < 4; ++i)
            af[i] = *(const short8*)&As[(wm * 64 + i * 16 + mlane) * 32 + kg];
#pragma unroll
        for (int j = 0; j < 4; ++j)
            bf[j] = *(const short8*)&Bs[(wn * 64 + j * 16 + mlane) * 32 + kg];
#pragma unroll
        for (int i = 0; i < 4; ++i)
#pragma unroll
            for (int j = 0; j < 4; ++j)
                acc[i][j] = __builtin_amdgcn_mfma_f32_16x16x32_bf16(af[i], bf[j], acc[i][j], 0, 0, 0);
    }

    const int rb  = (lane >> 4) * 4;
    const int col = lane & 15;
#pragma unroll
    for (int j = 0; j < 4; ++j) {
        const int n  = n0 + wn * 64 + j * 16 + col;
        const float bias_n = bias[n];
        const int h  = n >> 6;
        const int hd = n & 63;
#pragma unroll
        for (int i = 0; i < 4; ++i) {
#pragma unroll
            for (int r = 0; r < 4; ++r) {
                const int m = m0 + wm * 64 + i * 16 + rb + r;
                const int b = m >> 10;
                const int s = m & 1023;
                size_t addr;
                if (which == 2)
                    addr = (((size_t)(b * Hn + h)) * HDn + hd) * Sn + s;   // V transposed
                else
                    addr = (((size_t)(b * Hn + h)) * Sn + s) * HDn + hd;
                Out[addr] = f2bf((acc[i][j][r] + bias_n) * scale);
            }
        }
    }
}

// ---------------------------------------------------------------------------
// Streaming MFMA flash attention: NO LDS staging, NO per-kt barriers.
// Block = 32 q of one (b,h); 4 waves each own 4 contiguous kt tiles (same q).
// A-frags (K rows / V^T rows) loaded global->register as b128 (L2-resident).
// No-max softmax => partials exactly additive; one LDS combine at end.
// grid (32,16,4) = 2048 blocks, 8192 waves.
// ---------------------------------------------------------------------------
__global__ __launch_bounds__(256, 4) void attn_mfma(
    const ushort* __restrict__ Q, const ushort* __restrict__ K,
    const ushort* __restrict__ Vt, const uint* __restrict__ Mw,
    float* __restrict__ out)
{
    const int qsub = blockIdx.x, h = blockIdx.y, b = blockIdx.z;
    const int tid  = threadIdx.x;
    const int w    = tid >> 6, lane = tid & 63;
    const int col  = lane & 31, hi = lane >> 5;

    const size_t hb = ((size_t)(b * Hn + h)) * Sn * HDn;
    const ushort* Kg = K + hb;          // [key][dim]
    const ushort* Vg = Vt + hb;         // [dim][key]

    __shared__ __align__(16) float red[3 * 64 * 34];   // waves 1..3 partials, 26.1 KB

    // Q B-frags (registers): B[k=dim][n=q], n=col, k=kp*16+hi*8+i
    short8 qf[4];
#pragma unroll
    for (int kp = 0; kp < 4; ++kp)
        qf[kp] = *(const short8*)&Q[hb + (size_t)(qsub * 32 + col) * HDn + kp * 16 + hi * 8];

    float16v o_[2];
#pragma unroll
    for (int dt = 0; dt < 2; ++dt)
#pragma unroll
        for (int r = 0; r < 16; ++r) o_[dt][r] = 0.f;
    float ls = 0.f;

    // mask base: qsub = qt*4 + wq
    const int qt = qsub >> 2, wq = qsub & 3;
    const uint* mb0 = Mw + ((size_t)((b * 8 + qt) * 16) * 4 + wq) * 1024 + lane * 16;

#pragma unroll
    for (int kk = 0; kk < 4; ++kk) {
        const int kt = w * 4 + kk;
        const uint* mp = mb0 + (size_t)kt * 4096;

#pragma unroll
        for (int mt = 0; mt < 2; ++mt) {
            // ---- S^T tile: A = K rows direct from global, B = Q (regs) ----
            float16v s_;
#pragma unroll
            for (int r = 0; r < 16; ++r) s_[r] = 0.f;
            const ushort* krow = &Kg[(size_t)(kt * 64 + mt * 32 + col) * HDn + hi * 8];
#pragma unroll
            for (int kp = 0; kp < 4; ++kp) {
                short8 ak = *(const short8*)&krow[kp * 16];
                s_ = __builtin_amdgcn_mfma_f32_32x32x16_bf16(ak, qf[kp], s_, 0, 0, 0);
            }

            // ---- p = 2^s ; round-pack bf16 (perm) ; mask (and) ; sum ----
            uint4 mA = *(const uint4*)(mp + mt * 8);
            uint4 mB = *(const uint4*)(mp + mt * 8 + 4);
            const uint mka[8] = {mA.x, mA.y, mA.z, mA.w, mB.x, mB.y, mB.z, mB.w};
            unsigned up[8];
#pragma unroll
            for (int pr = 0; pr < 8; ++pr) {
                const unsigned e0 = __float_as_uint(exp2f(s_[2 * pr]))     + 0x8000u;
                const unsigned e1 = __float_as_uint(exp2f(s_[2 * pr + 1])) + 0x8000u;
                const unsigned u  = __builtin_amdgcn_perm(e1, e0, 0x07060302u) & mka[pr];
                up[pr] = u;
                ls += __uint_as_float(u << 16) + __uint_as_float(u & 0xffff0000u);
            }

            // ---- PV: B-frags via shfl_xor(32) C->B transform; V direct global ----
#pragma unroll
            for (int kkh = 0; kkh < 2; ++kkh) {
                const unsigned a0 = up[kkh * 4 + 0], a1 = up[kkh * 4 + 1];
                const unsigned a2 = up[kkh * 4 + 2], a3 = up[kkh * 4 + 3];
                const unsigned t0 = (unsigned)__shfl_xor((int)(hi ? a0 : a2), 32, 64);
                const unsigned t1 = (unsigned)__shfl_xor((int)(hi ? a1 : a3), 32, 64);
                union { short8 s; unsigned u[4]; } f;
                f.u[0] = hi ? t0 : a0;
                f.u[1] = hi ? t1 : a1;
                f.u[2] = hi ? a2 : t0;
                f.u[3] = hi ? a3 : t1;
                const int kp = mt * 2 + kkh;
#pragma unroll
                for (int dt = 0; dt < 2; ++dt) {
                    short8 av = *(const short8*)&Vg[(size_t)(dt * 32 + col) * Sn
                                                    + kt * 64 + kp * 16 + hi * 8];
                    o_[dt] = __builtin_amdgcn_mfma_f32_32x32x16_bf16(av, f.s, o_[dt], 0, 0, 0);
                }
            }
        }
    }

    // ---- combine 4 wave-partials (exactly additive) ----
    if (w > 0) {
        float* p = red + (size_t)((w - 1) * 64 + lane) * 34;
#pragma unroll
        for (int dt = 0; dt < 2; ++dt)
#pragma unroll
            for (int c = 0; c < 4; ++c)
                *(float4*)&p[dt * 16 + c * 4] = make_float4(
                    o_[dt][c * 4 + 0], o_[dt][c * 4 + 1],
                    o_[dt][c * 4 + 2], o_[dt][c * 4 + 3]);
        p[32] = ls;
    }
    __syncthreads();
    if (w == 0) {
#pragma unroll
        for (int ww = 0; ww < 3; ++ww) {
            const float* p = red + (size_t)(ww * 64 + lane) * 34;
#pragma unroll
            for (int dt = 0; dt < 2; ++dt)
#pragma unroll
                for (int r = 0; r < 16; ++r) o_[dt][r] += p[dt * 16 + r];
            ls += p[32];
        }

        float l = ls + (float)__shfl_xor((float)ls, 32, 64);
        const float inv = 1.0f / l;
        const int q = qsub * 32 + col;
        float* op = &out[((size_t)b * Sn + q) * Dn + h * 64];
#pragma unroll
        for (int dt = 0; dt < 2; ++dt)
#pragma unroll
            for (int rg = 0; rg < 4; ++rg) {
                const int d = dt * 32 + rg * 8 + hi * 4;
                float4 o4;
                o4.x = fmaxf(o_[dt][rg * 4 + 0] * inv, 0.0f);
                o4.y = fmaxf(o_[dt][rg * 4 + 1] * inv, 0.0f);
                o4.z = fmaxf(o_[dt][rg * 4 + 2] * inv, 0.0f);
                o4.w = fmaxf(o_[dt][rg * 4 + 3] * inv, 0.0f);
                *(float4*)&op[d] = o4;
            }
    }
}

extern "C" void kernel_launch(void* const* d_in, const int* in_sizes, int n_in,
                              void* d_out, int out_size, void* d_ws, size_t ws_size,
                              hipStream_t stream)
{
    const float* x   = (const float*)d_in[0];
    const float* adj = (const float*)d_in[1];
    const float* Wq  = (const float*)d_in[2];
    const float* bq  = (const float*)d_in[3];
    const float* Wk  = (const float*)d_in[4];
    const float* bk  = (const float*)d_in[5];
    const float* Wv  = (const float*)d_in[6];
    const float* bv  = (const float*)d_in[7];
    float* out = (float*)d_out;

    // ws (ushort): xb[4.19M] | Wt[3.15M] | Qb | Kb | Vb [4.19M ea] then Mb (uint, 8.4 MB)
    ushort* xb = (ushort*)d_ws;
    ushort* Wt = xb + (size_t)Bn * Sn * Dn;
    ushort* Qb = Wt + (size_t)3 * Dn * Dn;
    ushort* Kb = Qb + (size_t)Bn * Hn * Sn * HDn;
    ushort* Vb = Kb + (size_t)Bn * Hn * Sn * HDn;
    uint*   Mb = (uint*)(Vb + (size_t)Bn * Hn * Sn * HDn);

    convert_x<<<dim3(2048), 256, 0, stream>>>(x, xb);
    transpose_w<<<dim3(16, 16, 3), 256, 0, stream>>>(Wq, Wk, Wv, Wt);
    build_mask<<<dim3(512), 256, 0, stream>>>(adj, Mb);

    qkv_gemm<<<dim3(Dn / 128, (Bn * Sn) / 128, 3), 256, 0, stream>>>(
        xb, Wt, bq, bk, bv, Qb, Kb, Vb);

    attn_mfma<<<dim3(32, Hn, Bn), 256, 0, stream>>>(Qb, Kb, Vb, Mb, out);

    hipMemcpyAsync(out + (size_t)Bn * Sn * Dn, adj,
                   (size_t)Bn * Sn * Sn * sizeof(float),
                   hipMemcpyDeviceToDevice, stream);
}

// Round 10
// 199.991 us; speedup vs baseline: 1.1391x; 1.1391x over previous
//
#include <hip/hip_runtime.h>

constexpr int Bn  = 4;
constexpr int Sn  = 1024;
constexpr int Dn  = 1024;
constexpr int Hn  = 16;
constexpr int HDn = 64;

using short8   = __attribute__((ext_vector_type(8))) short;
using float4v  = __attribute__((ext_vector_type(4))) float;
using float16v = __attribute__((ext_vector_type(16))) float;

__device__ __forceinline__ ushort f2bf(float f) {
    union { float f; unsigned u; } v; v.f = f;
    unsigned r = v.u + 0x7fff + ((v.u >> 16) & 1);   // RNE
    return (ushort)(r >> 16);
}

__device__ __forceinline__ void gload16(const void* g, void* l) {
    __builtin_amdgcn_global_load_lds(
        (const __attribute__((address_space(1))) void*)g,
        (__attribute__((address_space(3))) void*)l, 16, 0, 0);
}

// ---------------------------------------------------------------------------
// x (fp32) -> xb (bf16 row-major)
// ---------------------------------------------------------------------------
__global__ __launch_bounds__(256) void convert_x(const float* __restrict__ x,
                                                 ushort* __restrict__ xb)
{
    const size_t i = ((size_t)blockIdx.x * 256 + threadIdx.x) * 8;
    float4 a = *(const float4*)&x[i];
    float4 b = *(const float4*)&x[i + 4];
    ushort o[8] = {f2bf(a.x), f2bf(a.y), f2bf(a.z), f2bf(a.w),
                   f2bf(b.x), f2bf(b.y), f2bf(b.z), f2bf(b.w)};
    *(uint4*)&xb[i] = *(const uint4*)o;
}

// ---------------------------------------------------------------------------
// W (K x N fp32) -> Wt (N x K bf16)
// ---------------------------------------------------------------------------
__global__ __launch_bounds__(256) void transpose_w(
    const float* __restrict__ Wq, const float* __restrict__ Wk,
    const float* __restrict__ Wv, ushort* __restrict__ Wt)
{
    const int which = blockIdx.z;
    const float* __restrict__ W = (which == 0) ? Wq : (which == 1) ? Wk : Wv;
    ushort* __restrict__ O = Wt + (size_t)which * Dn * Dn;

    const int k0 = blockIdx.x * 64;
    const int n0 = blockIdx.y * 64;
    const int t  = threadIdx.x;

    __shared__ __align__(16) ushort T[64 * 72];

    const int kl = t >> 4;
    const int nl = (t & 15) * 4;
#pragma unroll
    for (int p = 0; p < 4; ++p) {
        float4 w = *(const float4*)&W[(size_t)(k0 + p * 16 + kl) * Dn + n0 + nl];
        T[(nl + 0) * 72 + p * 16 + kl] = f2bf(w.x);
        T[(nl + 1) * 72 + p * 16 + kl] = f2bf(w.y);
        T[(nl + 2) * 72 + p * 16 + kl] = f2bf(w.z);
        T[(nl + 3) * 72 + p * 16 + kl] = f2bf(w.w);
    }
    __syncthreads();
    const int nr = t >> 2;
    const int kc = (t & 3) * 16;
    uint4 u0 = *(const uint4*)&T[nr * 72 + kc];
    uint4 u1 = *(const uint4*)&T[nr * 72 + kc + 8];
    *(uint4*)&O[(size_t)(n0 + nr) * Dn + k0 + kc]     = u0;
    *(uint4*)&O[(size_t)(n0 + nr) * Dn + k0 + kc + 8] = u1;
}

// ---------------------------------------------------------------------------
// build_mask_copy: coalesced adj read (LDS-staged), emits pair-halfword masks
// in PV-pack fragment order AND copies adj -> out (passthrough output).
// Mask layout (same as R7): dst = Mb + ((((b*8+qt)*16+kt)*4+w)*64+lane)*16;
// word mt*8+pr covers keys kt*64+mt*32+(2pr&3)+8*(2pr>>2)+4*hi+{0,1},
// q = qt*128+w*32+(lane&31).
// grid (8 qt, 8 ktp, 4 b), block 256; each block does 2 kt tiles.
// ---------------------------------------------------------------------------
__global__ __launch_bounds__(256) void build_mask_copy(
    const float* __restrict__ adj, uint* __restrict__ Mb,
    float* __restrict__ out)
{
    const int qt = blockIdx.x, ktp = blockIdx.y, b = blockIdx.z;
    const int tid = threadIdx.x;
    __shared__ char msk[128][68];

    const int lane = tid & 63, w = tid >> 6;
    const int col = lane & 31, hi = lane >> 5;

    float* ocopy = out + (size_t)Bn * Sn * Dn;

#pragma unroll
    for (int kk = 0; kk < 2; ++kk) {
        const int kt = ktp * 2 + kk;

        // stage: 128 q x 64 k, coalesced float4 reads + copy to out
        const int r16 = tid >> 4, c4 = (tid & 15) * 4;
#pragma unroll
        for (int p = 0; p < 8; ++p) {
            const int row = p * 16 + r16;
            const size_t gi = ((size_t)b * Sn + qt * 128 + row) * Sn + kt * 64 + c4;
            float4 a = *(const float4*)&adj[gi];
            *(float4*)&ocopy[gi] = a;
            char* mr = &msk[row][c4];
            mr[0] = a.x >= 0.5f; mr[1] = a.y >= 0.5f;
            mr[2] = a.z >= 0.5f; mr[3] = a.w >= 0.5f;
        }
        __syncthreads();

        // emit 16 words per thread, coalesced 64 B store
        uint words[16];
#pragma unroll
        for (int mt = 0; mt < 2; ++mt)
#pragma unroll
            for (int pr = 0; pr < 8; ++pr) {
                const int r0 = 2 * pr;
                const int kl = mt * 32 + (r0 & 3) + 8 * (r0 >> 2) + 4 * hi;
                words[mt * 8 + pr] = (msk[w * 32 + col][kl]     ? 0x0000FFFFu : 0u) |
                                     (msk[w * 32 + col][kl + 1] ? 0xFFFF0000u : 0u);
            }
        uint* dst = Mb + ((((size_t)(b * 8 + qt) * 16 + kt) * 4 + w) * 64 + lane) * 16;
#pragma unroll
        for (int c = 0; c < 4; ++c)
            *(uint4*)&dst[c * 4] =
                make_uint4(words[c*4], words[c*4+1], words[c*4+2], words[c*4+3]);
        __syncthreads();
    }
}

// ---------------------------------------------------------------------------
// bf16 MFMA GEMM: Q pre-scaled by 0.125*log2(e); Q/K -> [B,H,S,HD],
// V -> [B,H,HD,S]. Epilogue repacks C through LDS -> every global store is a
// contiguous 128 B run per thread (no scatter).
// ---------------------------------------------------------------------------
__global__ __launch_bounds__(256) void qkv_gemm(
    const ushort* __restrict__ xb, const ushort* __restrict__ Wt,
    const float* __restrict__ bq, const float* __restrict__ bk,
    const float* __restrict__ bv,
    ushort* __restrict__ Qb, ushort* __restrict__ Kb, ushort* __restrict__ Vb)
{
    const int which = blockIdx.z;
    const ushort* __restrict__ Bw   = Wt + (size_t)which * Dn * Dn;
    const float* __restrict__  bias = (which == 0) ? bq : (which == 1) ? bk : bv;
    ushort* __restrict__       Out  = (which == 0) ? Qb : (which == 1) ? Kb : Vb;
    const float scale = (which == 0) ? 0.18033688011112042f : 1.0f;  // 0.125*log2(e)

    const int n0   = blockIdx.x * 128;
    const int m0   = blockIdx.y * 128;
    const int tid  = threadIdx.x;
    const int wave = tid >> 6;
    const int lane = tid & 63;
    const int wm   = wave >> 1;
    const int wn   = wave & 1;

    // pool: As|Bs (16 KB) during K-loop; C2 (128 x 136 ushort) in epilogue
    __shared__ __align__(16) ushort pool[128 * 136];
    ushort* As = pool;
    ushort* Bs = pool + 128 * 32;

    const int L0 = wave * 64 + lane;
    const int r0s = L0 >> 2, c0s = (L0 & 3) * 8;
    const int L1 = L0 + 256;
    const int r1s = L1 >> 2, c1s = (L1 & 3) * 8;

    const ushort* pA0 = &xb[(size_t)(m0 + r0s) * Dn + c0s];
    const ushort* pA1 = &xb[(size_t)(m0 + r1s) * Dn + c1s];
    const ushort* pB0 = &Bw[(size_t)(n0 + r0s) * Dn + c0s];
    const ushort* pB1 = &Bw[(size_t)(n0 + r1s) * Dn + c1s];

    char* ldsA0 = (char*)As + wave * 1024;
    char* ldsA1 = (char*)As + wave * 1024 + 4096;
    char* ldsB0 = (char*)Bs + wave * 1024;
    char* ldsB1 = (char*)Bs + wave * 1024 + 4096;

    const int mlane = lane & 15;
    const int kg    = (lane >> 4) * 8;

    float4v acc[4][4];
    const float4v z4 = {0.f, 0.f, 0.f, 0.f};
#pragma unroll
    for (int i = 0; i < 4; ++i)
#pragma unroll
        for (int j = 0; j < 4; ++j) acc[i][j] = z4;

    for (int k0 = 0; k0 < Dn; k0 += 32) {
        __syncthreads();
        gload16(pA0, ldsA0);
        gload16(pA1, ldsA1);
        gload16(pB0, ldsB0);
        gload16(pB1, ldsB1);
        pA0 += 32; pA1 += 32; pB0 += 32; pB1 += 32;
        __syncthreads();

        short8 af[4], bf[4];
#pragma unroll
        for (int i = 0; i < 4; ++i)
            af[i] = *(const short8*)&As[(wm * 64 + i * 16 + mlane) * 32 + kg];
#pragma unroll
        for (int j = 0; j < 4; ++j)
            bf[j] = *(const short8*)&Bs[(wn * 64 + j * 16 + mlane) * 32 + kg];
#pragma unroll
        for (int i = 0; i < 4; ++i)
#pragma unroll
            for (int j = 0; j < 4; ++j)
                acc[i][j] = __builtin_amdgcn_mfma_f32_16x16x32_bf16(af[i], bf[j], acc[i][j], 0, 0, 0);
    }

    const int rb    = (lane >> 4) * 4;
    const int col16 = lane & 15;
    const int bb    = m0 >> 10;          // batch (block spans one)
    const int s0    = m0 & 1023;
    ushort* C2 = pool;

    __syncthreads();   // all waves done with As/Bs
    if (which == 2) {
        // V: pack n-major (m contiguous) -> rows are [hd][s] runs
#pragma unroll
        for (int j = 0; j < 4; ++j) {
            const int nl = wn * 64 + j * 16 + col16;
            const float bias_n = bias[n0 + nl];
#pragma unroll
            for (int i = 0; i < 4; ++i) {
                ushort h4[4];
#pragma unroll
                for (int r = 0; r < 4; ++r) h4[r] = f2bf(acc[i][j][r] + bias_n);
                *(uint2*)&C2[nl * 136 + wm * 64 + i * 16 + rb] = *(const uint2*)h4;
            }
        }
        __syncthreads();
        const int n  = tid >> 1, mh = (tid & 1) * 64;
        const int gn = n0 + n, hh = gn >> 6, hd = gn & 63;
        ushort* dst = &Out[(((size_t)(bb * Hn + hh)) * HDn + hd) * Sn + s0 + mh];
#pragma unroll
        for (int c = 0; c < 8; ++c)
            *(uint4*)&dst[c * 8] = *(const uint4*)&C2[n * 136 + mh + c * 8];
    } else {
        // Q/K: pack m-major (n contiguous) -> rows are [s][hd] runs
#pragma unroll
        for (int j = 0; j < 4; ++j) {
            const int nl = wn * 64 + j * 16 + col16;
            const float bias_n = bias[n0 + nl];
#pragma unroll
            for (int i = 0; i < 4; ++i)
#pragma unroll
                for (int r = 0; r < 4; ++r)
                    C2[(wm * 64 + i * 16 + rb + r) * 136 + nl] =
                        f2bf((acc[i][j][r] + bias_n) * scale);
        }
        __syncthreads();
        const int m  = tid >> 1, nh = (tid & 1) * 64;
        const int gn = n0 + nh, hh = gn >> 6;          // hd base = 0
        const int s  = s0 + m;
        ushort* dst = &Out[(((size_t)(bb * Hn + hh)) * Sn + s) * HDn];
#pragma unroll
        for (int c = 0; c < 8; ++c)
            *(uint4*)&dst[c * 8] = *(const uint4*)&C2[m * 136 + nh + c * 8];
    }
}

// ---------------------------------------------------------------------------
// MFMA flash attention (R7-proven): 32x32x16, P in registers (shfl C->B),
// pair-masks, exp2 softmax with deferred row sum.
// Block = 128 q of one (b,h): 4 waves x 32 q. grid (8,16,4) = 2 blocks/CU.
// LDS 36 KB, stride 72, double-buffered, global->reg prefetch.
// ---------------------------------------------------------------------------
__global__ __launch_bounds__(256, 2) void attn_mfma(
    const ushort* __restrict__ Q, const ushort* __restrict__ K,
    const ushort* __restrict__ Vt, const uint* __restrict__ Mw,
    float* __restrict__ out)
{
    const int qt = blockIdx.x, h = blockIdx.y, b = blockIdx.z;
    const int tid  = threadIdx.x;
    const int w    = tid >> 6, lane = tid & 63;
    const int col  = lane & 31, hi = lane >> 5;

    const size_t hb = ((size_t)(b * Hn + h)) * Sn * HDn;
    const ushort* Kg = K + hb;          // [key][dim]
    const ushort* Vg = Vt + hb;         // [dim][key]

    __shared__ __align__(16) ushort Ks[2][64 * 72];
    __shared__ __align__(16) ushort Vs[2][64 * 72];

    short8 qf[4];
#pragma unroll
    for (int kp = 0; kp < 4; ++kp)
        qf[kp] = *(const short8*)&Q[hb +
            (size_t)(qt * 128 + w * 32 + col) * HDn + kp * 16 + hi * 8];

    float16v o_[2];
#pragma unroll
    for (int dt = 0; dt < 2; ++dt)
#pragma unroll
        for (int r = 0; r < 16; ++r) o_[dt][r] = 0.f;
    float ls = 0.f;

    const int c0 = tid, c1 = tid + 256;
    const int la0 = (c0 >> 3) * 72 + (c0 & 7) * 8;
    const int la1 = (c1 >> 3) * 72 + (c1 & 7) * 8;

    uint4 k0 = *(const uint4*)&Kg[(size_t)(c0 >> 3) * HDn + (c0 & 7) * 8];
    uint4 k1 = *(const uint4*)&Kg[(size_t)(c1 >> 3) * HDn + (c1 & 7) * 8];
    uint4 v0 = *(const uint4*)&Vg[(size_t)(c0 >> 3) * Sn + (c0 & 7) * 8];
    uint4 v1 = *(const uint4*)&Vg[(size_t)(c1 >> 3) * Sn + (c1 & 7) * 8];
    *(uint4*)&Ks[0][la0] = k0;  *(uint4*)&Ks[0][la1] = k1;
    *(uint4*)&Vs[0][la0] = v0;  *(uint4*)&Vs[0][la1] = v1;
    __syncthreads();

    const uint* mbase = Mw + ((size_t)((b * 8 + qt) * 16) * 4 + w) * 1024 + lane * 16;

    for (int kt = 0; kt < 16; ++kt) {
        const int cur = kt & 1;
        if (kt < 15) {
            k0 = *(const uint4*)&Kg[(size_t)((kt + 1) * 64 + (c0 >> 3)) * HDn + (c0 & 7) * 8];
            k1 = *(const uint4*)&Kg[(size_t)((kt + 1) * 64 + (c1 >> 3)) * HDn + (c1 & 7) * 8];
            v0 = *(const uint4*)&Vg[(size_t)(c0 >> 3) * Sn + (kt + 1) * 64 + (c0 & 7) * 8];
            v1 = *(const uint4*)&Vg[(size_t)(c1 >> 3) * Sn + (kt + 1) * 64 + (c1 & 7) * 8];
        }
        const uint* mp = mbase + (size_t)kt * 4096;
        uint4 mk4[4];
        mk4[0] = *(const uint4*)(mp);
        mk4[1] = *(const uint4*)(mp + 4);
        mk4[2] = *(const uint4*)(mp + 8);
        mk4[3] = *(const uint4*)(mp + 12);
        const uint* mka = (const uint*)mk4;   // [mt*8 + pr]

#pragma unroll
        for (int mt = 0; mt < 2; ++mt) {
            float16v s_;
#pragma unroll
            for (int r = 0; r < 16; ++r) s_[r] = 0.f;
#pragma unroll
            for (int kp = 0; kp < 4; ++kp) {
                short8 ak = *(const short8*)&Ks[cur][(mt * 32 + col) * 72 + kp * 16 + hi * 8];
                s_ = __builtin_amdgcn_mfma_f32_32x32x16_bf16(ak, qf[kp], s_, 0, 0, 0);
            }

            unsigned up[8];
#pragma unroll
            for (int pr = 0; pr < 8; ++pr) {
                const unsigned e0 = __float_as_uint(exp2f(s_[2 * pr]))     + 0x8000u;
                const unsigned e1 = __float_as_uint(exp2f(s_[2 * pr + 1])) + 0x8000u;
                const unsigned u  = __builtin_amdgcn_perm(e1, e0, 0x07060302u) & mka[mt * 8 + pr];
                up[pr] = u;
                ls += __uint_as_float(u << 16) + __uint_as_float(u & 0xffff0000u);
            }

#pragma unroll
            for (int kh = 0; kh < 2; ++kh) {
                const unsigned a0 = up[kh * 4 + 0], a1 = up[kh * 4 + 1];
                const unsigned a2 = up[kh * 4 + 2], a3 = up[kh * 4 + 3];
                const unsigned t0 = (unsigned)__shfl_xor((int)(hi ? a0 : a2), 32, 64);
                const unsigned t1 = (unsigned)__shfl_xor((int)(hi ? a1 : a3), 32, 64);
                union { short8 s; unsigned u[4]; } f;
                f.u[0] = hi ? t0 : a0;
                f.u[1] = hi ? t1 : a1;
                f.u[2] = hi ? a2 : t0;
                f.u[3] = hi ? a3 : t1;
                const int kp = mt * 2 + kh;
#pragma unroll
                for (int dt = 0; dt < 2; ++dt) {
                    short8 av = *(const short8*)&Vs[cur][(dt * 32 + col) * 72 + kp * 16 + hi * 8];
                    o_[dt] = __builtin_amdgcn_mfma_f32_32x32x16_bf16(av, f.s, o_[dt], 0, 0, 0);
                }
            }
        }

        if (kt < 15) {
            const int nxt = cur ^ 1;
            *(uint4*)&Ks[nxt][la0] = k0;  *(uint4*)&Ks[nxt][la1] = k1;
            *(uint4*)&Vs[nxt][la0] = v0;  *(uint4*)&Vs[nxt][la1] = v1;
        }
        __syncthreads();
    }

    float l = ls + (float)__shfl_xor((float)ls, 32, 64);
    const float inv = 1.0f / l;
    const int q = qt * 128 + w * 32 + col;
    float* op = &out[((size_t)b * Sn + q) * Dn + h * 64];
#pragma unroll
    for (int dt = 0; dt < 2; ++dt)
#pragma unroll
        for (int rg = 0; rg < 4; ++rg) {
            const int d = dt * 32 + rg * 8 + hi * 4;
            float4 o4;
            o4.x = fmaxf(o_[dt][rg * 4 + 0] * inv, 0.0f);
            o4.y = fmaxf(o_[dt][rg * 4 + 1] * inv, 0.0f);
            o4.z = fmaxf(o_[dt][rg * 4 + 2] * inv, 0.0f);
            o4.w = fmaxf(o_[dt][rg * 4 + 3] * inv, 0.0f);
            *(float4*)&op[d] = o4;
        }
}

extern "C" void kernel_launch(void* const* d_in, const int* in_sizes, int n_in,
                              void* d_out, int out_size, void* d_ws, size_t ws_size,
                              hipStream_t stream)
{
    const float* x   = (const float*)d_in[0];
    const float* adj = (const float*)d_in[1];
    const float* Wq  = (const float*)d_in[2];
    const float* bq  = (const float*)d_in[3];
    const float* Wk  = (const float*)d_in[4];
    const float* bk  = (const float*)d_in[5];
    const float* Wv  = (const float*)d_in[6];
    const float* bv  = (const float*)d_in[7];
    float* out = (float*)d_out;

    // ws (ushort): xb[4.19M] | Wt[3.15M] | Qb | Kb | Vb [4.19M ea] then Mb (uint, 8.4 MB)
    ushort* xb = (ushort*)d_ws;
    ushort* Wt = xb + (size_t)Bn * Sn * Dn;
    ushort* Qb = Wt + (size_t)3 * Dn * Dn;
    ushort* Kb = Qb + (size_t)Bn * Hn * Sn * HDn;
    ushort* Vb = Kb + (size_t)Bn * Hn * Sn * HDn;
    uint*   Mb = (uint*)(Vb + (size_t)Bn * Hn * Sn * HDn);

    convert_x<<<dim3(2048), 256, 0, stream>>>(x, xb);
    transpose_w<<<dim3(16, 16, 3), 256, 0, stream>>>(Wq, Wk, Wv, Wt);
    build_mask_copy<<<dim3(8, 8, 4), 256, 0, stream>>>(adj, Mb, out);

    qkv_gemm<<<dim3(Dn / 128, (Bn * Sn) / 128, 3), 256, 0, stream>>>(
        xb, Wt, bq, bk, bv, Qb, Kb, Vb);

    attn_mfma<<<dim3(8, Hn, Bn), 256, 0, stream>>>(Qb, Kb, Vb, Mb, out);
}

// Round 11
// 188.044 us; speedup vs baseline: 1.2115x; 1.0635x over previous
//
#include <hip/hip_runtime.h>

constexpr int Bn  = 4;
constexpr int Sn  = 1024;
constexpr int Dn  = 1024;
constexpr int Hn  = 16;
constexpr int HDn = 64;

using short8   = __attribute__((ext_vector_type(8))) short;
using float4v  = __attribute__((ext_vector_type(4))) float;
using float16v = __attribute__((ext_vector_type(16))) float;

__device__ __forceinline__ ushort f2bf(float f) {
    union { float f; unsigned u; } v; v.f = f;
    unsigned r = v.u + 0x7fff + ((v.u >> 16) & 1);   // RNE
    return (ushort)(r >> 16);
}

__device__ __forceinline__ void gload16(const void* g, void* l) {
    __builtin_amdgcn_global_load_lds(
        (const __attribute__((address_space(1))) void*)g,
        (__attribute__((address_space(3))) void*)l, 16, 0, 0);
}

// ---------------------------------------------------------------------------
// prep — ONE dispatch, 3328 blocks:
//   [0,2048)    convert_x: x fp32 -> xb bf16
//   [2048,2816) transpose_w: W (KxN fp32) -> Wt (NxK bf16), 64x64 LDS tiles
//   [2816,3328) mask+copy: adj -> out passthrough AND pair-halfword masks in
//               PV-pack fragment order (512 blocks: one 128q x 64k tile each)
// Mask layout (R7/R10-proven): dst = Mb + ((((b*8+qt)*16+kt)*4+w)*64+lane)*16;
// word mt*8+pr covers keys kt*64+mt*32+(2pr&3)+8*(2pr>>2)+4*hi+{0,1},
// q = qt*128+w*32+(lane&31).
// ---------------------------------------------------------------------------
__global__ __launch_bounds__(256) void prep(
    const float* __restrict__ x,
    const float* __restrict__ Wq, const float* __restrict__ Wk,
    const float* __restrict__ Wv, const float* __restrict__ adj,
    ushort* __restrict__ xb, ushort* __restrict__ Wt, uint* __restrict__ Mb,
    float* __restrict__ out)
{
    const int bx  = blockIdx.x;
    const int tid = threadIdx.x;
    __shared__ __align__(16) ushort pool[64 * 72];   // 9216 B, aliased by msk

    if (bx < 2048) {
        // ---- convert_x ----
        const size_t i = ((size_t)bx * 256 + tid) * 8;
        float4 a = *(const float4*)&x[i];
        float4 b = *(const float4*)&x[i + 4];
        ushort o[8] = {f2bf(a.x), f2bf(a.y), f2bf(a.z), f2bf(a.w),
                       f2bf(b.x), f2bf(b.y), f2bf(b.z), f2bf(b.w)};
        *(uint4*)&xb[i] = *(const uint4*)o;
    } else if (bx < 2816) {
        // ---- transpose_w ----
        const int idx = bx - 2048;
        const int which = idx >> 8, rem = idx & 255;
        const float* __restrict__ W = (which == 0) ? Wq : (which == 1) ? Wk : Wv;
        ushort* __restrict__ O = Wt + (size_t)which * Dn * Dn;
        const int k0 = (rem & 15) * 64, n0 = (rem >> 4) * 64;
        ushort* T = pool;

        const int kl = tid >> 4, nl = (tid & 15) * 4;
#pragma unroll
        for (int p = 0; p < 4; ++p) {
            float4 w4 = *(const float4*)&W[(size_t)(k0 + p * 16 + kl) * Dn + n0 + nl];
            T[(nl + 0) * 72 + p * 16 + kl] = f2bf(w4.x);
            T[(nl + 1) * 72 + p * 16 + kl] = f2bf(w4.y);
            T[(nl + 2) * 72 + p * 16 + kl] = f2bf(w4.z);
            T[(nl + 3) * 72 + p * 16 + kl] = f2bf(w4.w);
        }
        __syncthreads();
        const int nr = tid >> 2, kc = (tid & 3) * 16;
        uint4 u0 = *(const uint4*)&T[nr * 72 + kc];
        uint4 u1 = *(const uint4*)&T[nr * 72 + kc + 8];
        *(uint4*)&O[(size_t)(n0 + nr) * Dn + k0 + kc]     = u0;
        *(uint4*)&O[(size_t)(n0 + nr) * Dn + k0 + kc + 8] = u1;
    } else {
        // ---- mask + adj->out copy: idx = ((b*8+qt)*16+kt) ----
        const int idx = bx - 2816;                 // 0..511
        const int kt = idx & 15, qt = (idx >> 4) & 7, b = idx >> 7;
        char* msk = (char*)pool;                   // [128][68], 8704 B <= 9216

        float* ocopy = out + (size_t)Bn * Sn * Dn;
        const int r16 = tid >> 4, c4 = (tid & 15) * 4;
#pragma unroll
        for (int p = 0; p < 8; ++p) {
            const int row = p * 16 + r16;
            const size_t gi = ((size_t)b * Sn + qt * 128 + row) * Sn + kt * 64 + c4;
            float4 a = *(const float4*)&adj[gi];
            *(float4*)&ocopy[gi] = a;
            char* mr = &msk[row * 68 + c4];
            mr[0] = a.x >= 0.5f; mr[1] = a.y >= 0.5f;
            mr[2] = a.z >= 0.5f; mr[3] = a.w >= 0.5f;
        }
        __syncthreads();

        const int lane = tid & 63, w = tid >> 6;
        const int col = lane & 31, hi = lane >> 5;
        uint words[16];
#pragma unroll
        for (int mt = 0; mt < 2; ++mt)
#pragma unroll
            for (int pr = 0; pr < 8; ++pr) {
                const int r0 = 2 * pr;
                const int kl = mt * 32 + (r0 & 3) + 8 * (r0 >> 2) + 4 * hi;
                const char* mr = &msk[(w * 32 + col) * 68];
                words[mt * 8 + pr] = (mr[kl]     ? 0x0000FFFFu : 0u) |
                                     (mr[kl + 1] ? 0xFFFF0000u : 0u);
            }
        uint* dst = Mb + ((((size_t)(b * 8 + qt) * 16 + kt) * 4 + w) * 64 + lane) * 16;
#pragma unroll
        for (int c = 0; c < 4; ++c)
            *(uint4*)&dst[c * 4] =
                make_uint4(words[c*4], words[c*4+1], words[c*4+2], words[c*4+3]);
    }
}

// ---------------------------------------------------------------------------
// bf16 MFMA GEMM (R7-exact): Q pre-scaled by 0.125*log2(e);
// Q/K -> [B,H,S,HD], V -> [B,H,HD,S]. Scatter epilogue (16-lane 32 B runs).
// ---------------------------------------------------------------------------
__global__ __launch_bounds__(256) void qkv_gemm(
    const ushort* __restrict__ xb, const ushort* __restrict__ Wt,
    const float* __restrict__ bq, const float* __restrict__ bk,
    const float* __restrict__ bv,
    ushort* __restrict__ Qb, ushort* __restrict__ Kb, ushort* __restrict__ Vb)
{
    const int which = blockIdx.z;
    const ushort* __restrict__ Bw   = Wt + (size_t)which * Dn * Dn;
    const float* __restrict__  bias = (which == 0) ? bq : (which == 1) ? bk : bv;
    ushort* __restrict__       Out  = (which == 0) ? Qb : (which == 1) ? Kb : Vb;
    const float scale = (which == 0) ? 0.18033688011112042f : 1.0f;  // 0.125*log2(e)

    const int n0   = blockIdx.x * 128;
    const int m0   = blockIdx.y * 128;
    const int tid  = threadIdx.x;
    const int wave = tid >> 6;
    const int lane = tid & 63;
    const int wm   = wave >> 1;
    const int wn   = wave & 1;

    __shared__ __align__(16) ushort As[128 * 32];
    __shared__ __align__(16) ushort Bs[128 * 32];

    const int L0 = wave * 64 + lane;
    const int r0s = L0 >> 2, c0s = (L0 & 3) * 8;
    const int L1 = L0 + 256;
    const int r1s = L1 >> 2, c1s = (L1 & 3) * 8;

    const ushort* pA0 = &xb[(size_t)(m0 + r0s) * Dn + c0s];
    const ushort* pA1 = &xb[(size_t)(m0 + r1s) * Dn + c1s];
    const ushort* pB0 = &Bw[(size_t)(n0 + r0s) * Dn + c0s];
    const ushort* pB1 = &Bw[(size_t)(n0 + r1s) * Dn + c1s];

    char* ldsA0 = (char*)As + wave * 1024;
    char* ldsA1 = (char*)As + wave * 1024 + 4096;
    char* ldsB0 = (char*)Bs + wave * 1024;
    char* ldsB1 = (char*)Bs + wave * 1024 + 4096;

    const int mlane = lane & 15;
    const int kg    = (lane >> 4) * 8;

    float4v acc[4][4];
    const float4v z4 = {0.f, 0.f, 0.f, 0.f};
#pragma unroll
    for (int i = 0; i < 4; ++i)
#pragma unroll
        for (int j = 0; j < 4; ++j) acc[i][j] = z4;

    for (int k0 = 0; k0 < Dn; k0 += 32) {
        __syncthreads();
        gload16(pA0, ldsA0);
        gload16(pA1, ldsA1);
        gload16(pB0, ldsB0);
        gload16(pB1, ldsB1);
        pA0 += 32; pA1 += 32; pB0 += 32; pB1 += 32;
        __syncthreads();

        short8 af[4], bf[4];
#pragma unroll
        for (int i = 0; i < 4; ++i)
            af[i] = *(const short8*)&As[(wm * 64 + i * 16 + mlane) * 32 + kg];
#pragma unroll
        for (int j = 0; j < 4; ++j)
            bf[j] = *(const short8*)&Bs[(wn * 64 + j * 16 + mlane) * 32 + kg];
#pragma unroll
        for (int i = 0; i < 4; ++i)
#pragma unroll
            for (int j = 0; j < 4; ++j)
                acc[i][j] = __builtin_amdgcn_mfma_f32_16x16x32_bf16(af[i], bf[j], acc[i][j], 0, 0, 0);
    }

    const int rb  = (lane >> 4) * 4;
    const int col = lane & 15;
#pragma unroll
    for (int j = 0; j < 4; ++j) {
        const int n  = n0 + wn * 64 + j * 16 + col;
        const float bias_n = bias[n];
        const int h  = n >> 6;
        const int hd = n & 63;
#pragma unroll
        for (int i = 0; i < 4; ++i) {
#pragma unroll
            for (int r = 0; r < 4; ++r) {
                const int m = m0 + wm * 64 + i * 16 + rb + r;
                const int b = m >> 10;
                const int s = m & 1023;
                size_t addr;
                if (which == 2)
                    addr = (((size_t)(b * Hn + h)) * HDn + hd) * Sn + s;   // V transposed
                else
                    addr = (((size_t)(b * Hn + h)) * Sn + s) * HDn + hd;
                Out[addr] = f2bf((acc[i][j][r] + bias_n) * scale);
            }
        }
    }
}

// ---------------------------------------------------------------------------
// MFMA flash attention (R7-proven): 32x32x16, P in registers (shfl C->B),
// pair-masks, exp2 softmax with deferred row sum.
// Block = 128 q of one (b,h): 4 waves x 32 q. grid (8,16,4) = 2 blocks/CU.
// LDS 36 KB, stride 72, double-buffered, global->reg prefetch.
// ---------------------------------------------------------------------------
__global__ __launch_bounds__(256, 2) void attn_mfma(
    const ushort* __restrict__ Q, const ushort* __restrict__ K,
    const ushort* __restrict__ Vt, const uint* __restrict__ Mw,
    float* __restrict__ out)
{
    const int qt = blockIdx.x, h = blockIdx.y, b = blockIdx.z;
    const int tid  = threadIdx.x;
    const int w    = tid >> 6, lane = tid & 63;
    const int col  = lane & 31, hi = lane >> 5;

    const size_t hb = ((size_t)(b * Hn + h)) * Sn * HDn;
    const ushort* Kg = K + hb;          // [key][dim]
    const ushort* Vg = Vt + hb;         // [dim][key]

    __shared__ __align__(16) ushort Ks[2][64 * 72];
    __shared__ __align__(16) ushort Vs[2][64 * 72];

    short8 qf[4];
#pragma unroll
    for (int kp = 0; kp < 4; ++kp)
        qf[kp] = *(const short8*)&Q[hb +
            (size_t)(qt * 128 + w * 32 + col) * HDn + kp * 16 + hi * 8];

    float16v o_[2];
#pragma unroll
    for (int dt = 0; dt < 2; ++dt)
#pragma unroll
        for (int r = 0; r < 16; ++r) o_[dt][r] = 0.f;
    float ls = 0.f;

    const int c0 = tid, c1 = tid + 256;
    const int la0 = (c0 >> 3) * 72 + (c0 & 7) * 8;
    const int la1 = (c1 >> 3) * 72 + (c1 & 7) * 8;

    uint4 k0 = *(const uint4*)&Kg[(size_t)(c0 >> 3) * HDn + (c0 & 7) * 8];
    uint4 k1 = *(const uint4*)&Kg[(size_t)(c1 >> 3) * HDn + (c1 & 7) * 8];
    uint4 v0 = *(const uint4*)&Vg[(size_t)(c0 >> 3) * Sn + (c0 & 7) * 8];
    uint4 v1 = *(const uint4*)&Vg[(size_t)(c1 >> 3) * Sn + (c1 & 7) * 8];
    *(uint4*)&Ks[0][la0] = k0;  *(uint4*)&Ks[0][la1] = k1;
    *(uint4*)&Vs[0][la0] = v0;  *(uint4*)&Vs[0][la1] = v1;
    __syncthreads();

    const uint* mbase = Mw + ((size_t)((b * 8 + qt) * 16) * 4 + w) * 1024 + lane * 16;

    for (int kt = 0; kt < 16; ++kt) {
        const int cur = kt & 1;
        if (kt < 15) {
            k0 = *(const uint4*)&Kg[(size_t)((kt + 1) * 64 + (c0 >> 3)) * HDn + (c0 & 7) * 8];
            k1 = *(const uint4*)&Kg[(size_t)((kt + 1) * 64 + (c1 >> 3)) * HDn + (c1 & 7) * 8];
            v0 = *(const uint4*)&Vg[(size_t)(c0 >> 3) * Sn + (kt + 1) * 64 + (c0 & 7) * 8];
            v1 = *(const uint4*)&Vg[(size_t)(c1 >> 3) * Sn + (kt + 1) * 64 + (c1 & 7) * 8];
        }
        const uint* mp = mbase + (size_t)kt * 4096;
        uint4 mk4[4];
        mk4[0] = *(const uint4*)(mp);
        mk4[1] = *(const uint4*)(mp + 4);
        mk4[2] = *(const uint4*)(mp + 8);
        mk4[3] = *(const uint4*)(mp + 12);
        const uint* mka = (const uint*)mk4;   // [mt*8 + pr]

#pragma unroll
        for (int mt = 0; mt < 2; ++mt) {
            float16v s_;
#pragma unroll
            for (int r = 0; r < 16; ++r) s_[r] = 0.f;
#pragma unroll
            for (int kp = 0; kp < 4; ++kp) {
                short8 ak = *(const short8*)&Ks[cur][(mt * 32 + col) * 72 + kp * 16 + hi * 8];
                s_ = __builtin_amdgcn_mfma_f32_32x32x16_bf16(ak, qf[kp], s_, 0, 0, 0);
            }

            unsigned up[8];
#pragma unroll
            for (int pr = 0; pr < 8; ++pr) {
                const unsigned e0 = __float_as_uint(exp2f(s_[2 * pr]))     + 0x8000u;
                const unsigned e1 = __float_as_uint(exp2f(s_[2 * pr + 1])) + 0x8000u;
                const unsigned u  = __builtin_amdgcn_perm(e1, e0, 0x07060302u) & mka[mt * 8 + pr];
                up[pr] = u;
                ls += __uint_as_float(u << 16) + __uint_as_float(u & 0xffff0000u);
            }

#pragma unroll
            for (int kh = 0; kh < 2; ++kh) {
                const unsigned a0 = up[kh * 4 + 0], a1 = up[kh * 4 + 1];
                const unsigned a2 = up[kh * 4 + 2], a3 = up[kh * 4 + 3];
                const unsigned t0 = (unsigned)__shfl_xor((int)(hi ? a0 : a2), 32, 64);
                const unsigned t1 = (unsigned)__shfl_xor((int)(hi ? a1 : a3), 32, 64);
                union { short8 s; unsigned u[4]; } f;
                f.u[0] = hi ? t0 : a0;
                f.u[1] = hi ? t1 : a1;
                f.u[2] = hi ? a2 : t0;
                f.u[3] = hi ? a3 : t1;
                const int kp = mt * 2 + kh;
#pragma unroll
                for (int dt = 0; dt < 2; ++dt) {
                    short8 av = *(const short8*)&Vs[cur][(dt * 32 + col) * 72 + kp * 16 + hi * 8];
                    o_[dt] = __builtin_amdgcn_mfma_f32_32x32x16_bf16(av, f.s, o_[dt], 0, 0, 0);
                }
            }
        }

        if (kt < 15) {
            const int nxt = cur ^ 1;
            *(uint4*)&Ks[nxt][la0] = k0;  *(uint4*)&Ks[nxt][la1] = k1;
            *(uint4*)&Vs[nxt][la0] = v0;  *(uint4*)&Vs[nxt][la1] = v1;
        }
        __syncthreads();
    }

    float l = ls + (float)__shfl_xor((float)ls, 32, 64);
    const float inv = 1.0f / l;
    const int q = qt * 128 + w * 32 + col;
    float* op = &out[((size_t)b * Sn + q) * Dn + h * 64];
#pragma unroll
    for (int dt = 0; dt < 2; ++dt)
#pragma unroll
        for (int rg = 0; rg < 4; ++rg) {
            const int d = dt * 32 + rg * 8 + hi * 4;
            float4 o4;
            o4.x = fmaxf(o_[dt][rg * 4 + 0] * inv, 0.0f);
            o4.y = fmaxf(o_[dt][rg * 4 + 1] * inv, 0.0f);
            o4.z = fmaxf(o_[dt][rg * 4 + 2] * inv, 0.0f);
            o4.w = fmaxf(o_[dt][rg * 4 + 3] * inv, 0.0f);
            *(float4*)&op[d] = o4;
        }
}

extern "C" void kernel_launch(void* const* d_in, const int* in_sizes, int n_in,
                              void* d_out, int out_size, void* d_ws, size_t ws_size,
                              hipStream_t stream)
{
    const float* x   = (const float*)d_in[0];
    const float* adj = (const float*)d_in[1];
    const float* Wq  = (const float*)d_in[2];
    const float* bq  = (const float*)d_in[3];
    const float* Wk  = (const float*)d_in[4];
    const float* bk  = (const float*)d_in[5];
    const float* Wv  = (const float*)d_in[6];
    const float* bv  = (const float*)d_in[7];
    float* out = (float*)d_out;

    // ws (ushort): xb[4.19M] | Wt[3.15M] | Qb | Kb | Vb [4.19M ea] then Mb (uint, 8.4 MB)
    ushort* xb = (ushort*)d_ws;
    ushort* Wt = xb + (size_t)Bn * Sn * Dn;
    ushort* Qb = Wt + (size_t)3 * Dn * Dn;
    ushort* Kb = Qb + (size_t)Bn * Hn * Sn * HDn;
    ushort* Vb = Kb + (size_t)Bn * Hn * Sn * HDn;
    uint*   Mb = (uint*)(Vb + (size_t)Bn * Hn * Sn * HDn);

    prep<<<dim3(3328), 256, 0, stream>>>(x, Wq, Wk, Wv, adj, xb, Wt, Mb, out);

    qkv_gemm<<<dim3(Dn / 128, (Bn * Sn) / 128, 3), 256, 0, stream>>>(
        xb, Wt, bq, bk, bv, Qb, Kb, Vb);

    attn_mfma<<<dim3(8, Hn, Bn), 256, 0, stream>>>(Qb, Kb, Vb, Mb, out);
}